// Round 6
// baseline (1083.811 us; speedup 1.0000x reference)
//
#include <hip/hip_runtime.h>
#include <math.h>

#define BB 2
#define SS 4096
#define DD 768
#define HH 12
#define LL 2
#define FF 3072
#define CC 256
#define MM 8192   // B*S
#define QB 128    // queries per attention block
#define QKVN 2304 // fused QKV row width

using frag8 = __attribute__((ext_vector_type(8))) short;   // 8 bf16
using f32x4 = __attribute__((ext_vector_type(4))) float;

// ---------- helpers ----------
__device__ __forceinline__ unsigned short f2b(float f) {
  unsigned u = __float_as_uint(f);
  u = u + 0x7fffu + ((u >> 16) & 1u);   // RNE
  return (unsigned short)(u >> 16);
}
__device__ __forceinline__ unsigned pack2(float a, float b) {
  return (unsigned)f2b(a) | ((unsigned)f2b(b) << 16);
}
__device__ __forceinline__ float b2f(unsigned short v) {
  return __uint_as_float(((unsigned)v) << 16);
}
__device__ __forceinline__ void unpack8(int4 t, float* f) {
  unsigned u;
  u = (unsigned)t.x; f[0] = __uint_as_float(u << 16); f[1] = __uint_as_float(u & 0xffff0000u);
  u = (unsigned)t.y; f[2] = __uint_as_float(u << 16); f[3] = __uint_as_float(u & 0xffff0000u);
  u = (unsigned)t.z; f[4] = __uint_as_float(u << 16); f[5] = __uint_as_float(u & 0xffff0000u);
  u = (unsigned)t.w; f[6] = __uint_as_float(u << 16); f[7] = __uint_as_float(u & 0xffff0000u);
}
__device__ __forceinline__ void reduce2(float& s1, float& s2) {
#pragma unroll
  for (int off = 32; off > 0; off >>= 1) {
    s1 += __shfl_down(s1, off);
    s2 += __shfl_down(s2, off);
  }
  __shared__ float r1[4], r2[4];
  const int lane = threadIdx.x & 63, wv = threadIdx.x >> 6;
  if (lane == 0) { r1[wv] = s1; r2[wv] = s2; }
  __syncthreads();
  s1 = r1[0] + r1[1] + r1[2] + r1[3];
  s2 = r2[0] + r2[1] + r2[2] + r2[3];
  __syncthreads();
}
// async global->LDS, 16B per lane; lds dest = wave-uniform base + lane*16
__device__ __forceinline__ void async16(const unsigned short* g, unsigned short* l) {
  __builtin_amdgcn_global_load_lds((__attribute__((address_space(1))) void*)(g),
                                   (__attribute__((address_space(3))) void*)(l), 16, 0, 0);
}

// ---------- batched weight transposes fp32(K,N) -> bf16(N,K) ----------
__global__ __launch_bounds__(256) void transpose_sq8(const float* __restrict__ Wq,
                                                     const float* __restrict__ Wk,
                                                     const float* __restrict__ Wv,
                                                     const float* __restrict__ Wo,
                                                     unsigned short* __restrict__ wt) {
  __shared__ float t[32][33];
  const int z = blockIdx.z, l = z >> 2, w = z & 3;
  const float* in = ((w == 0) ? Wq : (w == 1) ? Wk : (w == 2) ? Wv : Wo) + (size_t)l * 589824;
  unsigned short* out = wt + (size_t)l * 7077888 + (size_t)w * 589824;
  const int n0 = blockIdx.x * 32, k0 = blockIdx.y * 32;
  const int tx = threadIdx.x, ty = threadIdx.y;   // block (32,8)
#pragma unroll
  for (int i = 0; i < 32; i += 8) t[ty + i][tx] = in[(size_t)(k0 + ty + i) * 768 + n0 + tx];
  __syncthreads();
#pragma unroll
  for (int i = 0; i < 32; i += 8) out[(size_t)(n0 + ty + i) * 768 + k0 + tx] = f2b(t[tx][ty + i]);
}

__global__ __launch_bounds__(256) void transpose_bz(const float* __restrict__ in0,
                                                    unsigned short* __restrict__ out0,
                                                    int K, int N, size_t sStride, size_t dStride) {
  __shared__ float t[32][33];
  const float* in = in0 + (size_t)blockIdx.z * sStride;
  unsigned short* out = out0 + (size_t)blockIdx.z * dStride;
  const int n0 = blockIdx.x * 32, k0 = blockIdx.y * 32;
  const int tx = threadIdx.x, ty = threadIdx.y;
#pragma unroll
  for (int i = 0; i < 32; i += 8) t[ty + i][tx] = in[(size_t)(k0 + ty + i) * N + n0 + tx];
  __syncthreads();
#pragma unroll
  for (int i = 0; i < 32; i += 8) out[(size_t)(n0 + ty + i) * K + k0 + tx] = f2b(t[tx][ty + i]);
}

// ---------- embedding + LN ----------
__global__ __launch_bounds__(256) void embed_ln(const int* __restrict__ ids,
                                                const float* __restrict__ etok,
                                                const float* __restrict__ epos,
                                                const float* __restrict__ g,
                                                const float* __restrict__ bb,
                                                float* __restrict__ h32,
                                                unsigned short* __restrict__ hB) {
  const int row = blockIdx.x;
  const int s = row & (SS - 1);
  const int id = ids[row];
  float x[3];
#pragma unroll
  for (int i = 0; i < 3; i++) {
    int j = threadIdx.x + i * 256;
    x[i] = etok[(size_t)id * DD + j] + epos[(size_t)s * DD + j];
  }
  float s1 = x[0] + x[1] + x[2];
  float s2 = x[0] * x[0] + x[1] * x[1] + x[2] * x[2];
  reduce2(s1, s2);
  const float mean = s1 * (1.f / 768.f);
  const float var = s2 * (1.f / 768.f) - mean * mean;
  const float rs = rsqrtf(var + 1e-5f);
#pragma unroll
  for (int i = 0; i < 3; i++) {
    int j = threadIdx.x + i * 256;
    float y = (x[i] - mean) * rs * g[j] + bb[j];
    h32[(size_t)row * DD + j] = y;
    hB[(size_t)row * DD + j] = f2b(y);
  }
}

// ---------- residual + LN (optionally two delta buffers: split-K partials) ----------
__global__ __launch_bounds__(256) void ln_res(float* __restrict__ h32,
                                              const float* __restrict__ delta,
                                              const float* __restrict__ delta2,
                                              const float* __restrict__ g,
                                              const float* __restrict__ bb,
                                              unsigned short* __restrict__ hB) {
  const int row = blockIdx.x;
  float x[3];
#pragma unroll
  for (int i = 0; i < 3; i++) {
    int j = threadIdx.x + i * 256;
    x[i] = h32[(size_t)row * DD + j] + delta[(size_t)row * DD + j];
  }
  if (delta2) {
#pragma unroll
    for (int i = 0; i < 3; i++) {
      int j = threadIdx.x + i * 256;
      x[i] += delta2[(size_t)row * DD + j];
    }
  }
  float s1 = x[0] + x[1] + x[2];
  float s2 = x[0] * x[0] + x[1] * x[1] + x[2] * x[2];
  reduce2(s1, s2);
  const float mean = s1 * (1.f / 768.f);
  const float var = s2 * (1.f / 768.f) - mean * mean;
  const float rs = rsqrtf(var + 1e-5f);
#pragma unroll
  for (int i = 0; i < 3; i++) {
    int j = threadIdx.x + i * 256;
    float y = (x[i] - mean) * rs * g[j] + bb[j];
    h32[(size_t)row * DD + j] = y;
    hB[(size_t)row * DD + j] = f2b(y);
  }
}

// ---------- 128x128 bf16 MFMA GEMM (fp32 out, split-K) ----------
template <int EPI>
__global__ __launch_bounds__(256) void gemm_nt(const unsigned short* __restrict__ A,
                                               const unsigned short* __restrict__ Bt,
                                               const float* __restrict__ bias0,
                                               float* __restrict__ outF,
                                               float* __restrict__ outF2,
                                               int M, int N, int K) {
  __shared__ unsigned short sA[128 * 32];
  __shared__ unsigned short sB[128 * 32];
  const int tid = threadIdx.x;

  const int gx = gridDim.x;
  const int L = blockIdx.x + gx * blockIdx.y;
  const int slot = L >> 3;
  const int m0 = ((L & 7) + 8 * (slot / gx)) * 128;
  const int n0 = (slot % gx) * 128;

  const int kspan = K / gridDim.z;
  const int kbeg = blockIdx.z * kspan;

  const int wave = tid >> 6, lane = tid & 63;
  const int wm = (wave >> 1) * 64, wn = (wave & 1) * 64;
  const int quad = lane >> 4, r16 = lane & 15;

  const int srow = wave * 32 + (lane >> 2);
  const int scol = (lane & 3) * 8;
  const unsigned short* gA0 = A + (size_t)(m0 + srow) * K + kbeg + scol;
  const unsigned short* gA1 = gA0 + (size_t)16 * K;
  const unsigned short* gB0 = Bt + (size_t)(n0 + srow) * K + kbeg + scol;
  const unsigned short* gB1 = gB0 + (size_t)16 * K;
  unsigned short* lA0 = &sA[(wave * 32) * 32];
  unsigned short* lA1 = &sA[(wave * 32 + 16) * 32];
  unsigned short* lB0 = &sB[(wave * 32) * 32];
  unsigned short* lB1 = &sB[(wave * 32 + 16) * 32];

  f32x4 acc[4][4];
#pragma unroll
  for (int i = 0; i < 4; i++)
#pragma unroll
    for (int j = 0; j < 4; j++) acc[i][j] = (f32x4){0.f, 0.f, 0.f, 0.f};

  const int kiters = kspan >> 5;
  for (int kt = 0; kt < kiters; kt++) {
    const int k0 = kt << 5;
    __syncthreads();
    async16(gA0 + k0, lA0);
    async16(gA1 + k0, lA1);
    async16(gB0 + k0, lB0);
    async16(gB1 + k0, lB1);
    __syncthreads();   // drains vmcnt(0)
    frag8 af[4], bf[4];
#pragma unroll
    for (int i = 0; i < 4; i++)
      af[i] = *reinterpret_cast<const frag8*>(&sA[(wm + i * 16 + r16) * 32 + quad * 8]);
#pragma unroll
    for (int j = 0; j < 4; j++)
      bf[j] = *reinterpret_cast<const frag8*>(&sB[(wn + j * 16 + r16) * 32 + quad * 8]);
#pragma unroll
    for (int i = 0; i < 4; i++)
#pragma unroll
      for (int j = 0; j < 4; j++)
        acc[i][j] = __builtin_amdgcn_mfma_f32_16x16x32_bf16(af[i], bf[j], acc[i][j], 0, 0, 0);
  }

  float* dst = (blockIdx.z == 0) ? outF : outF2;
  const bool addb = (blockIdx.z == 0);

#pragma unroll
  for (int i = 0; i < 4; i++)
#pragma unroll
    for (int j = 0; j < 4; j++)
#pragma unroll
      for (int rr = 0; rr < 4; rr++) {
        const int row = m0 + wm + i * 16 + quad * 4 + rr;
        const int col = n0 + wn + j * 16 + r16;
        dst[(size_t)row * N + col] = acc[i][j][rr] + (addb ? bias0[col] : 0.f);
      }
}

// ---------- 256Mx128N bf16 MFMA GEMM (bf16 epilogues) ----------
// Wave owns 64x128 (acc 4x8). Halves B-panel re-reads vs 128x128.
// EPI 1: QKV row-major bf16 [M][2304], q-segment scaled 0.125 (block-uniform)
// EPI 2: tanh-GELU -> bf16 row-major
template <int EPI>
__global__ __launch_bounds__(256) void gemm_nt256(const unsigned short* __restrict__ A,
                                                  const unsigned short* __restrict__ Bt,
                                                  const float* __restrict__ bias0,
                                                  const float* __restrict__ bias1,
                                                  const float* __restrict__ bias2,
                                                  unsigned short* __restrict__ oq,
                                                  int M, int N, int K) {
  __shared__ unsigned short sA[256 * 32];
  __shared__ unsigned short sB[128 * 32];
  const int tid = threadIdx.x;

  const int gx = gridDim.x;
  const int L = blockIdx.x + gx * blockIdx.y;
  const int slot = L >> 3;
  const int m0 = ((L & 7) + 8 * (slot / gx)) * 256;
  const int n0 = (slot % gx) * 128;

  const int wave = tid >> 6, lane = tid & 63;
  const int quad = lane >> 4, r16 = lane & 15;

  // staging: wave w -> A rows [w*64, w*64+64) in 4 issues; B rows [w*32, w*32+32) in 2
  const int srow = lane >> 2;          // 0..15
  const int scol = (lane & 3) * 8;
  const unsigned short* gA = A + (size_t)(m0 + wave * 64 + srow) * K + scol;
  const unsigned short* gB = Bt + (size_t)(n0 + wave * 32 + srow) * K + scol;
  unsigned short* lA = &sA[(wave * 64) * 32];
  unsigned short* lB = &sB[(wave * 32) * 32];

  f32x4 acc[4][8];
#pragma unroll
  for (int i = 0; i < 4; i++)
#pragma unroll
    for (int j = 0; j < 8; j++) acc[i][j] = (f32x4){0.f, 0.f, 0.f, 0.f};

  const int kiters = K >> 5;
  for (int kt = 0; kt < kiters; kt++) {
    const int k0 = kt << 5;
    __syncthreads();
    async16(gA + k0, lA);
    async16(gA + (size_t)16 * K + k0, lA + 16 * 32);
    async16(gA + (size_t)32 * K + k0, lA + 32 * 32);
    async16(gA + (size_t)48 * K + k0, lA + 48 * 32);
    async16(gB + k0, lB);
    async16(gB + (size_t)16 * K + k0, lB + 16 * 32);
    __syncthreads();   // drains vmcnt(0)
    frag8 af[4], bf[8];
#pragma unroll
    for (int i = 0; i < 4; i++)
      af[i] = *reinterpret_cast<const frag8*>(&sA[(wave * 64 + i * 16 + r16) * 32 + quad * 8]);
#pragma unroll
    for (int j = 0; j < 8; j++)
      bf[j] = *reinterpret_cast<const frag8*>(&sB[(j * 16 + r16) * 32 + quad * 8]);
#pragma unroll
    for (int i = 0; i < 4; i++)
#pragma unroll
      for (int j = 0; j < 8; j++)
        acc[i][j] = __builtin_amdgcn_mfma_f32_16x16x32_bf16(af[i], bf[j], acc[i][j], 0, 0, 0);
  }

  // EPI1 block-uniform segment select (N=2304, 768 = 6 x 128-tiles)
  const int which = (EPI == 1) ? (n0 / 768) : 0;
  const float* bw = (EPI == 1) ? ((which == 0) ? bias0 : (which == 1) ? bias1 : bias2) : bias0;
  const float qsc = (EPI == 1 && which == 0) ? 0.125f : 1.f;
  const int cofs = which * 768;

#pragma unroll
  for (int i = 0; i < 4; i++)
#pragma unroll
    for (int j = 0; j < 8; j++)
#pragma unroll
      for (int rr = 0; rr < 4; rr++) {
        const int row = m0 + wave * 64 + i * 16 + quad * 4 + rr;
        const int col = n0 + j * 16 + r16;
        if (EPI == 1) {
          float v = (acc[i][j][rr] + bw[col - cofs]) * qsc;
          oq[(size_t)row * N + col] = f2b(v);
        } else {
          float v = acc[i][j][rr] + bias0[col];
          float y = 1.5957691216f * (v + 0.044715f * v * v * v);
          float ge = v / (1.f + __expf(-y));
          oq[(size_t)row * N + col] = f2b(ge);
        }
      }
}

// ---------- MFMA flash sliding-window attention (transposed scores) ----------
__global__ __launch_bounds__(256) void attn_win(const unsigned short* __restrict__ qkv,
                                                const int* __restrict__ mask,
                                                unsigned short* __restrict__ ctxB) {
  const int n = blockIdx.x, h = blockIdx.y, b = blockIdx.z;
  const int tid = threadIdx.x;
  const int wave = tid >> 6, lane = tid & 63;
  const int quad = lane >> 4, r16 = lane & 15;
  const size_t rowB = (size_t)(b * SS);

  __shared__ unsigned short sK[64 * 72];        // keys x d, stride 72
  __shared__ unsigned short sVt[64 * 72];       // d x keys, stride 72
  __shared__ unsigned short sP2[4][32 * 72];    // per-wave P^T: [q_local][key], stride 72
  __shared__ __align__(16) int sM[64];

  const int qw0 = n * QB + wave * 32;

  frag8 qf[2][2];
#pragma unroll
  for (int mt = 0; mt < 2; mt++)
#pragma unroll
    for (int kh = 0; kh < 2; kh++) {
      int4 t = *reinterpret_cast<const int4*>(
          qkv + (rowB + qw0 + mt * 16 + r16) * QKVN + h * 64 + kh * 32 + quad * 8);
      qf[mt][kh] = *reinterpret_cast<frag8*>(&t);
    }

  f32x4 oacc[4][2];   // [dt][mt]
#pragma unroll
  for (int dt = 0; dt < 4; dt++)
#pragma unroll
    for (int mt = 0; mt < 2; mt++) oacc[dt][mt] = (f32x4){0.f, 0.f, 0.f, 0.f};
  float mx[2], li[2];
#pragma unroll
  for (int mt = 0; mt < 2; mt++) { mx[mt] = -1e30f; li[mt] = 0.f; }

  const int kbase = n * QB - 256;
  for (int ch = -1; ch < 10; ch++) {
    const int kc = kbase + ch * 64;
    const bool isG = (ch < 0);
    __syncthreads();
    {
      const int key = tid >> 2, d0 = (tid & 3) * 16;
      const int kp = isG ? ((key == 0) ? 0 : -1) : kc + key;
      int4 a = make_int4(0, 0, 0, 0), c = make_int4(0, 0, 0, 0);
      if (kp >= 0 && kp < SS) {
        const unsigned short* src = qkv + (rowB + kp) * QKVN + 768 + h * 64 + d0;
        a = *reinterpret_cast<const int4*>(src);
        c = *reinterpret_cast<const int4*>(src + 8);
      }
      *reinterpret_cast<int4*>(&sK[key * 72 + d0]) = a;
      *reinterpret_cast<int4*>(&sK[key * 72 + d0 + 8]) = c;
    }
    {
      const int key = tid & 63, d0 = (tid >> 6) * 16;
      const int kp = isG ? ((key == 0) ? 0 : -1) : kc + key;
      int4 a = make_int4(0, 0, 0, 0), c = make_int4(0, 0, 0, 0);
      if (kp >= 0 && kp < SS) {
        const unsigned short* src = qkv + (rowB + kp) * QKVN + 1536 + h * 64 + d0;
        a = *reinterpret_cast<const int4*>(src);
        c = *reinterpret_cast<const int4*>(src + 8);
      }
      unsigned short e[16];
      *reinterpret_cast<int4*>(&e[0]) = a;
      *reinterpret_cast<int4*>(&e[8]) = c;
#pragma unroll
      for (int j = 0; j < 16; j++) sVt[(d0 + j) * 72 + key] = e[j];
    }
    if (tid < 64) {
      int ok;
      if (isG) ok = (tid == 0) ? mask[rowB] : 0;
      else {
        const int kp = kc + tid;
        ok = (kp >= 1 && kp < SS) ? mask[rowB + kp] : 0;
      }
      sM[tid] = ok;
    }
    __syncthreads();

    if (!isG && (kc > qw0 + 31 + 256 || kc + 63 < qw0 - 256)) continue;

    f32x4 sacc[4][2];
#pragma unroll
    for (int nt = 0; nt < 4; nt++)
#pragma unroll
      for (int mt = 0; mt < 2; mt++) sacc[nt][mt] = (f32x4){0.f, 0.f, 0.f, 0.f};
#pragma unroll
    for (int kh = 0; kh < 2; kh++) {
      frag8 kf[4];
#pragma unroll
      for (int nt = 0; nt < 4; nt++)
        kf[nt] = *reinterpret_cast<const frag8*>(&sK[(nt * 16 + r16) * 72 + kh * 32 + quad * 8]);
#pragma unroll
      for (int nt = 0; nt < 4; nt++)
#pragma unroll
        for (int mt = 0; mt < 2; mt++)
          sacc[nt][mt] = __builtin_amdgcn_mfma_f32_16x16x32_bf16(kf[nt], qf[mt][kh], sacc[nt][mt], 0, 0, 0);
    }

    int mv[4][4];
#pragma unroll
    for (int nt = 0; nt < 4; nt++) {
      int4 t = *reinterpret_cast<const int4*>(&sM[nt * 16 + quad * 4]);
      mv[nt][0] = t.x; mv[nt][1] = t.y; mv[nt][2] = t.z; mv[nt][3] = t.w;
    }

#pragma unroll
    for (int mt = 0; mt < 2; mt++) {
      const int qg = qw0 + mt * 16 + r16;
      float m_c = -1e30f;
#pragma unroll
      for (int nt = 0; nt < 4; nt++)
#pragma unroll
        for (int rr = 0; rr < 4; rr++) {
          const int kp = kc + nt * 16 + quad * 4 + rr;
          const bool valid = (mv[nt][rr] != 0) && (isG || (unsigned)(kp - qg + 256) <= 512u);
          const float s = valid ? sacc[nt][mt][rr] : -1e30f;
          sacc[nt][mt][rr] = s;
          m_c = fmaxf(m_c, s);
        }
      m_c = fmaxf(m_c, __shfl_xor(m_c, 16, 64));
      m_c = fmaxf(m_c, __shfl_xor(m_c, 32, 64));
      const float mnew = fmaxf(mx[mt], m_c);
      const float alpha = __expf(mx[mt] - mnew);
      mx[mt] = mnew;
      float s_c = 0.f;
#pragma unroll
      for (int nt = 0; nt < 4; nt++) {
        float pk[4];
#pragma unroll
        for (int rr = 0; rr < 4; rr++) {
          const float sv = sacc[nt][mt][rr];
          float p = __expf(sv - mnew);
          p = (sv > -5e29f) ? p : 0.f;
          s_c += p;
          pk[rr] = p;
        }
        uint2 w;
        w.x = pack2(pk[0], pk[1]);
        w.y = pack2(pk[2], pk[3]);
        *reinterpret_cast<uint2*>(&sP2[wave][(mt * 16 + r16) * 72 + nt * 16 + quad * 4]) = w;
      }
      s_c += __shfl_xor(s_c, 16, 64);
      s_c += __shfl_xor(s_c, 32, 64);
      li[mt] = li[mt] * alpha + s_c;
#pragma unroll
      for (int dt = 0; dt < 4; dt++)
#pragma unroll
        for (int rr = 0; rr < 4; rr++) oacc[dt][mt][rr] *= alpha;
    }

#pragma unroll
    for (int kh = 0; kh < 2; kh++) {
      frag8 vf[4], pf[2];
#pragma unroll
      for (int dt = 0; dt < 4; dt++)
        vf[dt] = *reinterpret_cast<const frag8*>(&sVt[(dt * 16 + r16) * 72 + kh * 32 + quad * 8]);
#pragma unroll
      for (int mt = 0; mt < 2; mt++)
        pf[mt] = *reinterpret_cast<const frag8*>(&sP2[wave][(mt * 16 + r16) * 72 + kh * 32 + quad * 8]);
#pragma unroll
      for (int dt = 0; dt < 4; dt++)
#pragma unroll
        for (int mt = 0; mt < 2; mt++)
          oacc[dt][mt] = __builtin_amdgcn_mfma_f32_16x16x32_bf16(vf[dt], pf[mt], oacc[dt][mt], 0, 0, 0);
    }
  }

#pragma unroll
  for (int mt = 0; mt < 2; mt++) {
    const float inv = 1.f / li[mt];
    const int qg = qw0 + mt * 16 + r16;
#pragma unroll
    for (int dt = 0; dt < 4; dt++) {
      uint2 w;
      w.x = pack2(oacc[dt][mt][0] * inv, oacc[dt][mt][1] * inv);
      w.y = pack2(oacc[dt][mt][2] * inv, oacc[dt][mt][3] * inv);
      *reinterpret_cast<uint2*>(ctxB + (rowB + qg) * DD + h * 64 + dt * 16 + quad * 4) = w;
    }
  }
}

// ---------- full attention for query 0: split-K phase 1 ----------
__global__ __launch_bounds__(256) void attn_r0_part(const unsigned short* __restrict__ qkv,
                                                    const int* __restrict__ mask,
                                                    float* __restrict__ part) {
  const int ch = blockIdx.x, h = blockIdx.y, b = blockIdx.z;
  const int tid = threadIdx.x;
  const int lane = tid & 63, wave = tid >> 6;
  const size_t rowB = (size_t)(b * SS);

  __shared__ float sQ[64];
  __shared__ float wmx[4], wls[4];
  __shared__ float sPp[256];
  __shared__ float sO[4][64];
  if (tid < 8) {
    int4 t = *reinterpret_cast<const int4*>(qkv + rowB * QKVN + h * 64 + tid * 8);
    float f[8]; unpack8(t, f);
#pragma unroll
    for (int j = 0; j < 8; j++) sQ[tid * 8 + j] = f[j];
  }
  __syncthreads();

  const int key = ch * 256 + tid;
  float sc;
  {
    float s = 0.f;
    const unsigned short* kp = qkv + (rowB + key) * QKVN + 768 + h * 64;
#pragma unroll
    for (int i = 0; i < 8; i++) {
      int4 t = *reinterpret_cast<const int4*>(kp + i * 8);
      float f[8]; unpack8(t, f);
#pragma unroll
      for (int j = 0; j < 8; j++) s = fmaf(sQ[i * 8 + j], f[j], s);
    }
    sc = (mask[rowB + key] != 0) ? s : -1e9f;
  }
  float m = sc;
#pragma unroll
  for (int off = 1; off < 64; off <<= 1) m = fmaxf(m, __shfl_xor(m, off, 64));
  if (lane == 0) wmx[wave] = m;
  __syncthreads();
  const float Mx = fmaxf(fmaxf(wmx[0], wmx[1]), fmaxf(wmx[2], wmx[3]));
  const float p = __expf(sc - Mx);
  float ls = p;
#pragma unroll
  for (int off = 1; off < 64; off <<= 1) ls += __shfl_xor(ls, off, 64);
  sPp[tid] = p;
  if (lane == 0) wls[wave] = ls;
  __syncthreads();

  float acc = 0.f;
  const unsigned short* vb = qkv + (rowB + ch * 256 + wave * 64) * QKVN + 1536 + h * 64 + lane;
#pragma unroll 4
  for (int t = 0; t < 64; t++)
    acc = fmaf(sPp[wave * 64 + t], b2f(vb[(size_t)t * QKVN]), acc);
  sO[wave][lane] = acc;
  __syncthreads();
  if (tid < 64) {
    float* pp = part + ((size_t)((b * HH + h) * 16 + ch)) * 68;
    pp[tid] = sO[0][tid] + sO[1][tid] + sO[2][tid] + sO[3][tid];
    if (tid == 0) {
      pp[64] = Mx;
      pp[65] = wls[0] + wls[1] + wls[2] + wls[3];
    }
  }
}

// ---------- phase 2 ----------
__global__ __launch_bounds__(64) void attn_r0_comb(const float* __restrict__ part,
                                                   unsigned short* __restrict__ ctxB) {
  const int h = blockIdx.x, b = blockIdx.y;
  const int tid = threadIdx.x;
  const float* base = part + ((size_t)((b * HH + h) * 16)) * 68;
  float M = -1e30f;
#pragma unroll
  for (int c = 0; c < 16; c++) M = fmaxf(M, base[c * 68 + 64]);
  float L = 0.f, o = 0.f;
#pragma unroll
  for (int c = 0; c < 16; c++) {
    const float w = __expf(base[c * 68 + 64] - M);
    L += base[c * 68 + 65] * w;
    o = fmaf(w, base[c * 68 + tid], o);
  }
  ctxB[((size_t)(b * SS)) * DD + h * 64 + tid] = f2b(o / L);
}

// ---------- classifier ----------
__global__ __launch_bounds__(256) void cls_head(const float* __restrict__ h32,
                                                const float* __restrict__ W,
                                                const float* __restrict__ bc,
                                                float* __restrict__ out) {
  const int b = blockIdx.x;
  const float* hr = h32 + (size_t)b * SS * DD;
  float p0 = 0.f, p1 = 0.f, p2 = 0.f;
  for (int d = threadIdx.x; d < DD; d += 256) {
    const float x = hr[d];
    p0 = fmaf(x, W[d * 3 + 0], p0);
    p1 = fmaf(x, W[d * 3 + 1], p1);
    p2 = fmaf(x, W[d * 3 + 2], p2);
  }
  __shared__ float r0[256], r1[256], r2[256];
  r0[threadIdx.x] = p0; r1[threadIdx.x] = p1; r2[threadIdx.x] = p2;
  __syncthreads();
  if (threadIdx.x == 0) {
    float s0 = 0.f, s1 = 0.f, s2 = 0.f;
    for (int t = 0; t < 256; t++) { s0 += r0[t]; s1 += r1[t]; s2 += r2[t]; }
    out[b * 3 + 0] = s0 + bc[0];
    out[b * 3 + 1] = s1 + bc[1];
    out[b * 3 + 2] = s2 + bc[2];
  }
}

// ---------- workspace layout (bytes) ----------
static const size_t OFF_WT = 0;             // transposed weights, bf16
static const size_t OFF_H32 = 28311552;     // MM*DD fp32
static const size_t OFF_HB = 53477376;      // MM*DD bf16
static const size_t OFF_QKV = 66060288;     // MM*2304 bf16 (QKV; later split-K partial #2)
static const size_t OFF_CTX = 103809024;    // MM*DD bf16
static const size_t OFF_DELTA = 116391936;  // MM*DD fp32 (r0 partials; split-K partial #1)
static const size_t OFF_F1 = 141557760;     // MM*FF bf16
static const size_t WS_NEEDED = 191889408;

extern "C" void kernel_launch(void* const* d_in, const int* in_sizes, int n_in,
                              void* d_out, int out_size, void* d_ws, size_t ws_size,
                              hipStream_t stream) {
  (void)in_sizes; (void)n_in; (void)out_size;
  if (ws_size < WS_NEEDED) return;

  const int* ids = (const int*)d_in[0];
  const int* mask = (const int*)d_in[1];
  const float* emb_tok = (const float*)d_in[2];
  const float* emb_pos = (const float*)d_in[3];
  const float* eg = (const float*)d_in[4];
  const float* eb = (const float*)d_in[5];
  const float* Wq = (const float*)d_in[6];
  const float* bq = (const float*)d_in[7];
  const float* Wk = (const float*)d_in[8];
  const float* bk = (const float*)d_in[9];
  const float* Wv = (const float*)d_in[10];
  const float* bv = (const float*)d_in[11];
  const float* Wo = (const float*)d_in[12];
  const float* bo = (const float*)d_in[13];
  const float* ln1g = (const float*)d_in[14];
  const float* ln1b = (const float*)d_in[15];
  const float* W1 = (const float*)d_in[16];
  const float* b1 = (const float*)d_in[17];
  const float* W2 = (const float*)d_in[18];
  const float* b2 = (const float*)d_in[19];
  const float* ln2g = (const float*)d_in[20];
  const float* ln2b = (const float*)d_in[21];
  const float* clsW = (const float*)d_in[22];
  const float* clsb = (const float*)d_in[23];
  float* out = (float*)d_out;

  char* ws = (char*)d_ws;
  unsigned short* wt = (unsigned short*)(ws + OFF_WT);
  float* h32 = (float*)(ws + OFF_H32);
  unsigned short* hB = (unsigned short*)(ws + OFF_HB);
  unsigned short* qkvB = (unsigned short*)(ws + OFF_QKV);
  unsigned short* ctxB = (unsigned short*)(ws + OFF_CTX);
  float* delta = (float*)(ws + OFF_DELTA);
  float* aux = (float*)(ws + OFF_QKV);       // split-K partial #2 (QKV region dead by then)
  unsigned short* f1B = (unsigned short*)(ws + OFF_F1);

  transpose_sq8<<<dim3(24, 24, 8), dim3(32, 8), 0, stream>>>(Wq, Wk, Wv, Wo, wt);
  transpose_bz<<<dim3(96, 24, 2), dim3(32, 8), 0, stream>>>(W1, wt + 2359296, 768, 3072,
                                                            2359296, 7077888);
  transpose_bz<<<dim3(24, 96, 2), dim3(32, 8), 0, stream>>>(W2, wt + 4718592, 3072, 768,
                                                            2359296, 7077888);

  embed_ln<<<MM, 256, 0, stream>>>(ids, emb_tok, emb_pos, eg, eb, h32, hB);

  for (int l = 0; l < 2; l++) {
    const size_t lw = (size_t)l * 7077888;
    // QKV: 256x128 tiles, grid (N/128, M/256)
    gemm_nt256<1><<<dim3(18, 32), 256, 0, stream>>>(hB, wt + lw, bq + l * 768, bk + l * 768,
                                                    bv + l * 768, qkvB, MM, QKVN, 768);
    attn_win<<<dim3(SS / QB, 12, 2), 256, 0, stream>>>(qkvB, mask, ctxB);
    attn_r0_part<<<dim3(16, 12, 2), 256, 0, stream>>>(qkvB, mask, delta);
    attn_r0_comb<<<dim3(12, 2), 64, 0, stream>>>(delta, ctxB);
    // Wo: 128x128 split-K=2
    gemm_nt<0><<<dim3(6, 64, 2), 256, 0, stream>>>(ctxB, wt + lw + 1769472, bo + l * 768,
                                                   delta, aux, MM, 768, 768);
    ln_res<<<MM, 256, 0, stream>>>(h32, delta, aux, ln1g + l * 768, ln1b + l * 768, hB);
    // FFN1: 256x128 tiles + fused GELU
    gemm_nt256<2><<<dim3(24, 32), 256, 0, stream>>>(hB, wt + lw + 2359296, b1 + l * 3072,
                                                    nullptr, nullptr, f1B, MM, 3072, 768);
    // FFN2: 128x128 split-K=2
    gemm_nt<0><<<dim3(6, 64, 2), 256, 0, stream>>>(f1B, wt + lw + 4718592, b2 + l * 768,
                                                   delta, aux, MM, 768, 3072);
    ln_res<<<MM, 256, 0, stream>>>(h32, delta, aux, ln2g + l * 768, ln2b + l * 768, hB);
  }

  cls_head<<<dim3(BB), 256, 0, stream>>>(h32, clsW, clsb, out);
}

// Round 7
// 895.785 us; speedup vs baseline: 1.2099x; 1.2099x over previous
//
#include <hip/hip_runtime.h>
#include <math.h>

#define BB 2
#define SS 4096
#define DD 768
#define HH 12
#define LL 2
#define FF 3072
#define CC 256
#define MM 8192   // B*S
#define QB 128    // queries per attention block
#define QKVN 2304 // fused QKV row width

using frag8 = __attribute__((ext_vector_type(8))) short;   // 8 bf16
using f32x4 = __attribute__((ext_vector_type(4))) float;

// ---------- helpers ----------
__device__ __forceinline__ unsigned short f2b(float f) {
  unsigned u = __float_as_uint(f);
  u = u + 0x7fffu + ((u >> 16) & 1u);   // RNE
  return (unsigned short)(u >> 16);
}
__device__ __forceinline__ unsigned pack2(float a, float b) {
  return (unsigned)f2b(a) | ((unsigned)f2b(b) << 16);
}
__device__ __forceinline__ float b2f(unsigned short v) {
  return __uint_as_float(((unsigned)v) << 16);
}
__device__ __forceinline__ void unpack8(int4 t, float* f) {
  unsigned u;
  u = (unsigned)t.x; f[0] = __uint_as_float(u << 16); f[1] = __uint_as_float(u & 0xffff0000u);
  u = (unsigned)t.y; f[2] = __uint_as_float(u << 16); f[3] = __uint_as_float(u & 0xffff0000u);
  u = (unsigned)t.z; f[4] = __uint_as_float(u << 16); f[5] = __uint_as_float(u & 0xffff0000u);
  u = (unsigned)t.w; f[6] = __uint_as_float(u << 16); f[7] = __uint_as_float(u & 0xffff0000u);
}
__device__ __forceinline__ void reduce2(float& s1, float& s2) {
#pragma unroll
  for (int off = 32; off > 0; off >>= 1) {
    s1 += __shfl_down(s1, off);
    s2 += __shfl_down(s2, off);
  }
  __shared__ float r1[4], r2[4];
  const int lane = threadIdx.x & 63, wv = threadIdx.x >> 6;
  if (lane == 0) { r1[wv] = s1; r2[wv] = s2; }
  __syncthreads();
  s1 = r1[0] + r1[1] + r1[2] + r1[3];
  s2 = r2[0] + r2[1] + r2[2] + r2[3];
  __syncthreads();
}
// async global->LDS, 16B per lane; lds dest = wave-uniform base + lane*16
__device__ __forceinline__ void async16(const unsigned short* g, unsigned short* l) {
  __builtin_amdgcn_global_load_lds((__attribute__((address_space(1))) void*)(g),
                                   (__attribute__((address_space(3))) void*)(l), 16, 0, 0);
}

// ---------- batched weight transposes fp32(K,N) -> bf16(N,K) ----------
__global__ __launch_bounds__(256) void transpose_sq8(const float* __restrict__ Wq,
                                                     const float* __restrict__ Wk,
                                                     const float* __restrict__ Wv,
                                                     const float* __restrict__ Wo,
                                                     unsigned short* __restrict__ wt) {
  __shared__ float t[32][33];
  const int z = blockIdx.z, l = z >> 2, w = z & 3;
  const float* in = ((w == 0) ? Wq : (w == 1) ? Wk : (w == 2) ? Wv : Wo) + (size_t)l * 589824;
  unsigned short* out = wt + (size_t)l * 7077888 + (size_t)w * 589824;
  const int n0 = blockIdx.x * 32, k0 = blockIdx.y * 32;
  const int tx = threadIdx.x, ty = threadIdx.y;   // block (32,8)
#pragma unroll
  for (int i = 0; i < 32; i += 8) t[ty + i][tx] = in[(size_t)(k0 + ty + i) * 768 + n0 + tx];
  __syncthreads();
#pragma unroll
  for (int i = 0; i < 32; i += 8) out[(size_t)(n0 + ty + i) * 768 + k0 + tx] = f2b(t[tx][ty + i]);
}

__global__ __launch_bounds__(256) void transpose_bz(const float* __restrict__ in0,
                                                    unsigned short* __restrict__ out0,
                                                    int K, int N, size_t sStride, size_t dStride) {
  __shared__ float t[32][33];
  const float* in = in0 + (size_t)blockIdx.z * sStride;
  unsigned short* out = out0 + (size_t)blockIdx.z * dStride;
  const int n0 = blockIdx.x * 32, k0 = blockIdx.y * 32;
  const int tx = threadIdx.x, ty = threadIdx.y;
#pragma unroll
  for (int i = 0; i < 32; i += 8) t[ty + i][tx] = in[(size_t)(k0 + ty + i) * N + n0 + tx];
  __syncthreads();
#pragma unroll
  for (int i = 0; i < 32; i += 8) out[(size_t)(n0 + ty + i) * K + k0 + tx] = f2b(t[tx][ty + i]);
}

// ---------- embedding + LN (bf16 stream out) ----------
__global__ __launch_bounds__(256) void embed_ln(const int* __restrict__ ids,
                                                const float* __restrict__ etok,
                                                const float* __restrict__ epos,
                                                const float* __restrict__ g,
                                                const float* __restrict__ bb,
                                                unsigned short* __restrict__ hB) {
  const int row = blockIdx.x;
  const int s = row & (SS - 1);
  const int id = ids[row];
  float x[3];
#pragma unroll
  for (int i = 0; i < 3; i++) {
    int j = threadIdx.x + i * 256;
    x[i] = etok[(size_t)id * DD + j] + epos[(size_t)s * DD + j];
  }
  float s1 = x[0] + x[1] + x[2];
  float s2 = x[0] * x[0] + x[1] * x[1] + x[2] * x[2];
  reduce2(s1, s2);
  const float mean = s1 * (1.f / 768.f);
  const float var = s2 * (1.f / 768.f) - mean * mean;
  const float rs = rsqrtf(var + 1e-5f);
#pragma unroll
  for (int i = 0; i < 3; i++) {
    int j = threadIdx.x + i * 256;
    hB[(size_t)row * DD + j] = f2b((x[i] - mean) * rs * g[j] + bb[j]);
  }
}

// ---------- residual + LN, all-bf16 stream (post-LN arch: stream == LN out) ----------
__global__ __launch_bounds__(256) void ln_res(unsigned short* __restrict__ hB,
                                              const unsigned short* __restrict__ d1,
                                              const unsigned short* __restrict__ d2,
                                              const float* __restrict__ g,
                                              const float* __restrict__ bb) {
  const int row = blockIdx.x;
  const size_t base = (size_t)row * DD;
  float x[3];
#pragma unroll
  for (int i = 0; i < 3; i++) {
    int j = threadIdx.x + i * 256;
    x[i] = b2f(hB[base + j]) + b2f(d1[base + j]) + b2f(d2[base + j]);
  }
  float s1 = x[0] + x[1] + x[2];
  float s2 = x[0] * x[0] + x[1] * x[1] + x[2] * x[2];
  reduce2(s1, s2);
  const float mean = s1 * (1.f / 768.f);
  const float var = s2 * (1.f / 768.f) - mean * mean;
  const float rs = rsqrtf(var + 1e-5f);
#pragma unroll
  for (int i = 0; i < 3; i++) {
    int j = threadIdx.x + i * 256;
    hB[base + j] = f2b((x[i] - mean) * rs * g[j] + bb[j]);
  }
}

// ---------- 128x128 bf16 MFMA GEMM:  C = A(M,K) @ Bt(N,K)^T + bias ----------
// XCD-swizzled; split-K via gridDim.z (EPI0: z=0 -> o16a (+bias), z=1 -> o16b).
// EPI 0: bf16 row-major partials
// EPI 1: QKV row-major bf16 [M][2304], q-segment scaled 0.125 (block-uniform)
// EPI 2: tanh-GELU -> bf16 row-major
template <int EPI>
__global__ __launch_bounds__(256) void gemm_nt(const unsigned short* __restrict__ A,
                                               const unsigned short* __restrict__ Bt,
                                               const float* __restrict__ bias0,
                                               const float* __restrict__ bias1,
                                               const float* __restrict__ bias2,
                                               unsigned short* __restrict__ o16a,
                                               unsigned short* __restrict__ o16b,
                                               int M, int N, int K) {
  __shared__ unsigned short sA[128 * 32];
  __shared__ unsigned short sB[128 * 32];
  const int tid = threadIdx.x;

  // XCD swizzle: blocks on one XCD (L%8) get consecutive slots
  const int gx = gridDim.x;
  const int L = blockIdx.x + gx * blockIdx.y;
  const int slot = L >> 3;
  const int m0 = ((L & 7) + 8 * (slot / gx)) * 128;
  const int n0 = (slot % gx) * 128;

  const int kspan = K / gridDim.z;
  const int kbeg = blockIdx.z * kspan;

  const int wave = tid >> 6, lane = tid & 63;
  const int wm = (wave >> 1) * 64, wn = (wave & 1) * 64;
  const int quad = lane >> 4, r16 = lane & 15;

  const int srow = wave * 32 + (lane >> 2);
  const int scol = (lane & 3) * 8;
  const unsigned short* gA0 = A + (size_t)(m0 + srow) * K + kbeg + scol;
  const unsigned short* gA1 = gA0 + (size_t)16 * K;
  const unsigned short* gB0 = Bt + (size_t)(n0 + srow) * K + kbeg + scol;
  const unsigned short* gB1 = gB0 + (size_t)16 * K;
  unsigned short* lA0 = &sA[(wave * 32) * 32];
  unsigned short* lA1 = &sA[(wave * 32 + 16) * 32];
  unsigned short* lB0 = &sB[(wave * 32) * 32];
  unsigned short* lB1 = &sB[(wave * 32 + 16) * 32];

  f32x4 acc[4][4];
#pragma unroll
  for (int i = 0; i < 4; i++)
#pragma unroll
    for (int j = 0; j < 4; j++) acc[i][j] = (f32x4){0.f, 0.f, 0.f, 0.f};

  const int kiters = kspan >> 5;
  for (int kt = 0; kt < kiters; kt++) {
    const int k0 = kt << 5;
    __syncthreads();
    async16(gA0 + k0, lA0);
    async16(gA1 + k0, lA1);
    async16(gB0 + k0, lB0);
    async16(gB1 + k0, lB1);
    __syncthreads();   // drains vmcnt(0)
    frag8 af[4], bf[4];
#pragma unroll
    for (int i = 0; i < 4; i++)
      af[i] = *reinterpret_cast<const frag8*>(&sA[(wm + i * 16 + r16) * 32 + quad * 8]);
#pragma unroll
    for (int j = 0; j < 4; j++)
      bf[j] = *reinterpret_cast<const frag8*>(&sB[(wn + j * 16 + r16) * 32 + quad * 8]);
#pragma unroll
    for (int i = 0; i < 4; i++)
#pragma unroll
      for (int j = 0; j < 4; j++)
        acc[i][j] = __builtin_amdgcn_mfma_f32_16x16x32_bf16(af[i], bf[j], acc[i][j], 0, 0, 0);
  }

  // EPI1 block-uniform segment select (N=2304, 768 = 6 x 128-tiles)
  const int which = (EPI == 1) ? (n0 / 768) : 0;
  const float* bw = (EPI == 1) ? ((which == 0) ? bias0 : (which == 1) ? bias1 : bias2) : bias0;
  const float qsc = (EPI == 1 && which == 0) ? 0.125f : 1.f;
  const int cofs = which * 768;

  unsigned short* dst = (EPI == 0 && blockIdx.z != 0) ? o16b : o16a;
  const bool addb = (blockIdx.z == 0);

#pragma unroll
  for (int i = 0; i < 4; i++)
#pragma unroll
    for (int j = 0; j < 4; j++)
#pragma unroll
      for (int rr = 0; rr < 4; rr++) {
        const int row = m0 + wm + i * 16 + quad * 4 + rr;
        const int col = n0 + wn + j * 16 + r16;
        if (EPI == 0) {
          dst[(size_t)row * N + col] = f2b(acc[i][j][rr] + (addb ? bias0[col] : 0.f));
        } else if (EPI == 1) {
          float v = (acc[i][j][rr] + bw[col - cofs]) * qsc;
          dst[(size_t)row * N + col] = f2b(v);
        } else {
          float v = acc[i][j][rr] + bias0[col];
          float y = 1.5957691216f * (v + 0.044715f * v * v * v);
          float ge = v / (1.f + __expf(-y));
          dst[(size_t)row * N + col] = f2b(ge);
        }
      }
}

// ---------- MFMA flash sliding-window attention (transposed scores) ----------
__global__ __launch_bounds__(256) void attn_win(const unsigned short* __restrict__ qkv,
                                                const int* __restrict__ mask,
                                                unsigned short* __restrict__ ctxB) {
  const int n = blockIdx.x, h = blockIdx.y, b = blockIdx.z;
  const int tid = threadIdx.x;
  const int wave = tid >> 6, lane = tid & 63;
  const int quad = lane >> 4, r16 = lane & 15;
  const size_t rowB = (size_t)(b * SS);

  __shared__ unsigned short sK[64 * 72];        // keys x d, stride 72
  __shared__ unsigned short sVt[64 * 72];       // d x keys, stride 72
  __shared__ unsigned short sP2[4][32 * 72];    // per-wave P^T: [q_local][key], stride 72
  __shared__ __align__(16) int sM[64];

  const int qw0 = n * QB + wave * 32;

  frag8 qf[2][2];
#pragma unroll
  for (int mt = 0; mt < 2; mt++)
#pragma unroll
    for (int kh = 0; kh < 2; kh++) {
      int4 t = *reinterpret_cast<const int4*>(
          qkv + (rowB + qw0 + mt * 16 + r16) * QKVN + h * 64 + kh * 32 + quad * 8);
      qf[mt][kh] = *reinterpret_cast<frag8*>(&t);
    }

  f32x4 oacc[4][2];   // [dt][mt]
#pragma unroll
  for (int dt = 0; dt < 4; dt++)
#pragma unroll
    for (int mt = 0; mt < 2; mt++) oacc[dt][mt] = (f32x4){0.f, 0.f, 0.f, 0.f};
  float mx[2], li[2];
#pragma unroll
  for (int mt = 0; mt < 2; mt++) { mx[mt] = -1e30f; li[mt] = 0.f; }

  const int kbase = n * QB - 256;
  for (int ch = -1; ch < 10; ch++) {
    const int kc = kbase + ch * 64;
    const bool isG = (ch < 0);
    __syncthreads();
    {
      const int key = tid >> 2, d0 = (tid & 3) * 16;
      const int kp = isG ? ((key == 0) ? 0 : -1) : kc + key;
      int4 a = make_int4(0, 0, 0, 0), c = make_int4(0, 0, 0, 0);
      if (kp >= 0 && kp < SS) {
        const unsigned short* src = qkv + (rowB + kp) * QKVN + 768 + h * 64 + d0;
        a = *reinterpret_cast<const int4*>(src);
        c = *reinterpret_cast<const int4*>(src + 8);
      }
      *reinterpret_cast<int4*>(&sK[key * 72 + d0]) = a;
      *reinterpret_cast<int4*>(&sK[key * 72 + d0 + 8]) = c;
    }
    {
      const int key = tid & 63, d0 = (tid >> 6) * 16;
      const int kp = isG ? ((key == 0) ? 0 : -1) : kc + key;
      int4 a = make_int4(0, 0, 0, 0), c = make_int4(0, 0, 0, 0);
      if (kp >= 0 && kp < SS) {
        const unsigned short* src = qkv + (rowB + kp) * QKVN + 1536 + h * 64 + d0;
        a = *reinterpret_cast<const int4*>(src);
        c = *reinterpret_cast<const int4*>(src + 8);
      }
      unsigned short e[16];
      *reinterpret_cast<int4*>(&e[0]) = a;
      *reinterpret_cast<int4*>(&e[8]) = c;
#pragma unroll
      for (int j = 0; j < 16; j++) sVt[(d0 + j) * 72 + key] = e[j];
    }
    if (tid < 64) {
      int ok;
      if (isG) ok = (tid == 0) ? mask[rowB] : 0;
      else {
        const int kp = kc + tid;
        ok = (kp >= 1 && kp < SS) ? mask[rowB + kp] : 0;
      }
      sM[tid] = ok;
    }
    __syncthreads();

    if (!isG && (kc > qw0 + 31 + 256 || kc + 63 < qw0 - 256)) continue;

    f32x4 sacc[4][2];
#pragma unroll
    for (int nt = 0; nt < 4; nt++)
#pragma unroll
      for (int mt = 0; mt < 2; mt++) sacc[nt][mt] = (f32x4){0.f, 0.f, 0.f, 0.f};
#pragma unroll
    for (int kh = 0; kh < 2; kh++) {
      frag8 kf[4];
#pragma unroll
      for (int nt = 0; nt < 4; nt++)
        kf[nt] = *reinterpret_cast<const frag8*>(&sK[(nt * 16 + r16) * 72 + kh * 32 + quad * 8]);
#pragma unroll
      for (int nt = 0; nt < 4; nt++)
#pragma unroll
        for (int mt = 0; mt < 2; mt++)
          sacc[nt][mt] = __builtin_amdgcn_mfma_f32_16x16x32_bf16(kf[nt], qf[mt][kh], sacc[nt][mt], 0, 0, 0);
    }

    int mv[4][4];
#pragma unroll
    for (int nt = 0; nt < 4; nt++) {
      int4 t = *reinterpret_cast<const int4*>(&sM[nt * 16 + quad * 4]);
      mv[nt][0] = t.x; mv[nt][1] = t.y; mv[nt][2] = t.z; mv[nt][3] = t.w;
    }

#pragma unroll
    for (int mt = 0; mt < 2; mt++) {
      const int qg = qw0 + mt * 16 + r16;
      float m_c = -1e30f;
#pragma unroll
      for (int nt = 0; nt < 4; nt++)
#pragma unroll
        for (int rr = 0; rr < 4; rr++) {
          const int kp = kc + nt * 16 + quad * 4 + rr;
          const bool valid = (mv[nt][rr] != 0) && (isG || (unsigned)(kp - qg + 256) <= 512u);
          const float s = valid ? sacc[nt][mt][rr] : -1e30f;
          sacc[nt][mt][rr] = s;
          m_c = fmaxf(m_c, s);
        }
      m_c = fmaxf(m_c, __shfl_xor(m_c, 16, 64));
      m_c = fmaxf(m_c, __shfl_xor(m_c, 32, 64));
      const float mnew = fmaxf(mx[mt], m_c);
      const float alpha = __expf(mx[mt] - mnew);
      mx[mt] = mnew;
      float s_c = 0.f;
#pragma unroll
      for (int nt = 0; nt < 4; nt++) {
        float pk[4];
#pragma unroll
        for (int rr = 0; rr < 4; rr++) {
          const float sv = sacc[nt][mt][rr];
          float p = __expf(sv - mnew);
          p = (sv > -5e29f) ? p : 0.f;
          s_c += p;
          pk[rr] = p;
        }
        uint2 w;
        w.x = pack2(pk[0], pk[1]);
        w.y = pack2(pk[2], pk[3]);
        *reinterpret_cast<uint2*>(&sP2[wave][(mt * 16 + r16) * 72 + nt * 16 + quad * 4]) = w;
      }
      s_c += __shfl_xor(s_c, 16, 64);
      s_c += __shfl_xor(s_c, 32, 64);
      li[mt] = li[mt] * alpha + s_c;
#pragma unroll
      for (int dt = 0; dt < 4; dt++)
#pragma unroll
        for (int rr = 0; rr < 4; rr++) oacc[dt][mt][rr] *= alpha;
    }

#pragma unroll
    for (int kh = 0; kh < 2; kh++) {
      frag8 vf[4], pf[2];
#pragma unroll
      for (int dt = 0; dt < 4; dt++)
        vf[dt] = *reinterpret_cast<const frag8*>(&sVt[(dt * 16 + r16) * 72 + kh * 32 + quad * 8]);
#pragma unroll
      for (int mt = 0; mt < 2; mt++)
        pf[mt] = *reinterpret_cast<const frag8*>(&sP2[wave][(mt * 16 + r16) * 72 + kh * 32 + quad * 8]);
#pragma unroll
      for (int dt = 0; dt < 4; dt++)
#pragma unroll
        for (int mt = 0; mt < 2; mt++)
          oacc[dt][mt] = __builtin_amdgcn_mfma_f32_16x16x32_bf16(vf[dt], pf[mt], oacc[dt][mt], 0, 0, 0);
    }
  }

#pragma unroll
  for (int mt = 0; mt < 2; mt++) {
    const float inv = 1.f / li[mt];
    const int qg = qw0 + mt * 16 + r16;
#pragma unroll
    for (int dt = 0; dt < 4; dt++) {
      uint2 w;
      w.x = pack2(oacc[dt][mt][0] * inv, oacc[dt][mt][1] * inv);
      w.y = pack2(oacc[dt][mt][2] * inv, oacc[dt][mt][3] * inv);
      *reinterpret_cast<uint2*>(ctxB + (rowB + qg) * DD + h * 64 + dt * 16 + quad * 4) = w;
    }
  }
}

// ---------- full attention for query 0: split-K phase 1 ----------
__global__ __launch_bounds__(256) void attn_r0_part(const unsigned short* __restrict__ qkv,
                                                    const int* __restrict__ mask,
                                                    float* __restrict__ part) {
  const int ch = blockIdx.x, h = blockIdx.y, b = blockIdx.z;
  const int tid = threadIdx.x;
  const int lane = tid & 63, wave = tid >> 6;
  const size_t rowB = (size_t)(b * SS);

  __shared__ float sQ[64];
  __shared__ float wmx[4], wls[4];
  __shared__ float sPp[256];
  __shared__ float sO[4][64];
  if (tid < 8) {
    int4 t = *reinterpret_cast<const int4*>(qkv + rowB * QKVN + h * 64 + tid * 8);
    float f[8]; unpack8(t, f);
#pragma unroll
    for (int j = 0; j < 8; j++) sQ[tid * 8 + j] = f[j];
  }
  __syncthreads();

  const int key = ch * 256 + tid;
  float sc;
  {
    float s = 0.f;
    const unsigned short* kp = qkv + (rowB + key) * QKVN + 768 + h * 64;
#pragma unroll
    for (int i = 0; i < 8; i++) {
      int4 t = *reinterpret_cast<const int4*>(kp + i * 8);
      float f[8]; unpack8(t, f);
#pragma unroll
      for (int j = 0; j < 8; j++) s = fmaf(sQ[i * 8 + j], f[j], s);
    }
    sc = (mask[rowB + key] != 0) ? s : -1e9f;
  }
  float m = sc;
#pragma unroll
  for (int off = 1; off < 64; off <<= 1) m = fmaxf(m, __shfl_xor(m, off, 64));
  if (lane == 0) wmx[wave] = m;
  __syncthreads();
  const float Mx = fmaxf(fmaxf(wmx[0], wmx[1]), fmaxf(wmx[2], wmx[3]));
  const float p = __expf(sc - Mx);
  float ls = p;
#pragma unroll
  for (int off = 1; off < 64; off <<= 1) ls += __shfl_xor(ls, off, 64);
  sPp[tid] = p;
  if (lane == 0) wls[wave] = ls;
  __syncthreads();

  float acc = 0.f;
  const unsigned short* vb = qkv + (rowB + ch * 256 + wave * 64) * QKVN + 1536 + h * 64 + lane;
#pragma unroll 4
  for (int t = 0; t < 64; t++)
    acc = fmaf(sPp[wave * 64 + t], b2f(vb[(size_t)t * QKVN]), acc);
  sO[wave][lane] = acc;
  __syncthreads();
  if (tid < 64) {
    float* pp = part + ((size_t)((b * HH + h) * 16 + ch)) * 68;
    pp[tid] = sO[0][tid] + sO[1][tid] + sO[2][tid] + sO[3][tid];
    if (tid == 0) {
      pp[64] = Mx;
      pp[65] = wls[0] + wls[1] + wls[2] + wls[3];
    }
  }
}

// ---------- phase 2 ----------
__global__ __launch_bounds__(64) void attn_r0_comb(const float* __restrict__ part,
                                                   unsigned short* __restrict__ ctxB) {
  const int h = blockIdx.x, b = blockIdx.y;
  const int tid = threadIdx.x;
  const float* base = part + ((size_t)((b * HH + h) * 16)) * 68;
  float M = -1e30f;
#pragma unroll
  for (int c = 0; c < 16; c++) M = fmaxf(M, base[c * 68 + 64]);
  float L = 0.f, o = 0.f;
#pragma unroll
  for (int c = 0; c < 16; c++) {
    const float w = __expf(base[c * 68 + 64] - M);
    L += base[c * 68 + 65] * w;
    o = fmaf(w, base[c * 68 + tid], o);
  }
  ctxB[((size_t)(b * SS)) * DD + h * 64 + tid] = f2b(o / L);
}

// ---------- classifier (bf16 stream in) ----------
__global__ __launch_bounds__(256) void cls_head(const unsigned short* __restrict__ hB,
                                                const float* __restrict__ W,
                                                const float* __restrict__ bc,
                                                float* __restrict__ out) {
  const int b = blockIdx.x;
  const unsigned short* hr = hB + (size_t)b * SS * DD;
  float p0 = 0.f, p1 = 0.f, p2 = 0.f;
  for (int d = threadIdx.x; d < DD; d += 256) {
    const float x = b2f(hr[d]);
    p0 = fmaf(x, W[d * 3 + 0], p0);
    p1 = fmaf(x, W[d * 3 + 1], p1);
    p2 = fmaf(x, W[d * 3 + 2], p2);
  }
  __shared__ float r0[256], r1[256], r2[256];
  r0[threadIdx.x] = p0; r1[threadIdx.x] = p1; r2[threadIdx.x] = p2;
  __syncthreads();
  if (threadIdx.x == 0) {
    float s0 = 0.f, s1 = 0.f, s2 = 0.f;
    for (int t = 0; t < 256; t++) { s0 += r0[t]; s1 += r1[t]; s2 += r2[t]; }
    out[b * 3 + 0] = s0 + bc[0];
    out[b * 3 + 1] = s1 + bc[1];
    out[b * 3 + 2] = s2 + bc[2];
  }
}

// ---------- workspace layout (bytes) ----------
static const size_t OFF_WT = 0;              // 28,311,552 transposed weights bf16
static const size_t OFF_HB = 28311552;       // MM*DD bf16 stream (12.58 MB)
static const size_t OFF_QKV = 40894464;      // MM*2304 bf16 (75.5 MB)
static const size_t OFF_CTX = 116391936;     // MM*DD bf16
static const size_t OFF_D1 = 128974848;      // MM*DD bf16 partial #1 (also r0 fp32 partials)
static const size_t OFF_D2 = 141557760;      // MM*DD bf16 partial #2
static const size_t OFF_F1 = 154140672;      // MM*FF bf16 (50.3 MB)
static const size_t WS_NEEDED = 204472320;

extern "C" void kernel_launch(void* const* d_in, const int* in_sizes, int n_in,
                              void* d_out, int out_size, void* d_ws, size_t ws_size,
                              hipStream_t stream) {
  (void)in_sizes; (void)n_in; (void)out_size;
  if (ws_size < WS_NEEDED) return;

  const int* ids = (const int*)d_in[0];
  const int* mask = (const int*)d_in[1];
  const float* emb_tok = (const float*)d_in[2];
  const float* emb_pos = (const float*)d_in[3];
  const float* eg = (const float*)d_in[4];
  const float* eb = (const float*)d_in[5];
  const float* Wq = (const float*)d_in[6];
  const float* bq = (const float*)d_in[7];
  const float* Wk = (const float*)d_in[8];
  const float* bk = (const float*)d_in[9];
  const float* Wv = (const float*)d_in[10];
  const float* bv = (const float*)d_in[11];
  const float* Wo = (const float*)d_in[12];
  const float* bo = (const float*)d_in[13];
  const float* ln1g = (const float*)d_in[14];
  const float* ln1b = (const float*)d_in[15];
  const float* W1 = (const float*)d_in[16];
  const float* b1 = (const float*)d_in[17];
  const float* W2 = (const float*)d_in[18];
  const float* b2 = (const float*)d_in[19];
  const float* ln2g = (const float*)d_in[20];
  const float* ln2b = (const float*)d_in[21];
  const float* clsW = (const float*)d_in[22];
  const float* clsb = (const float*)d_in[23];
  float* out = (float*)d_out;

  char* ws = (char*)d_ws;
  unsigned short* wt = (unsigned short*)(ws + OFF_WT);
  unsigned short* hB = (unsigned short*)(ws + OFF_HB);
  unsigned short* qkvB = (unsigned short*)(ws + OFF_QKV);
  unsigned short* ctxB = (unsigned short*)(ws + OFF_CTX);
  unsigned short* d1 = (unsigned short*)(ws + OFF_D1);
  unsigned short* d2 = (unsigned short*)(ws + OFF_D2);
  float* r0part = (float*)(ws + OFF_D1);     // reused before Wo GEMM overwrites
  unsigned short* f1B = (unsigned short*)(ws + OFF_F1);

  transpose_sq8<<<dim3(24, 24, 8), dim3(32, 8), 0, stream>>>(Wq, Wk, Wv, Wo, wt);
  transpose_bz<<<dim3(96, 24, 2), dim3(32, 8), 0, stream>>>(W1, wt + 2359296, 768, 3072,
                                                            2359296, 7077888);
  transpose_bz<<<dim3(24, 96, 2), dim3(32, 8), 0, stream>>>(W2, wt + 4718592, 3072, 768,
                                                            2359296, 7077888);

  embed_ln<<<MM, 256, 0, stream>>>(ids, emb_tok, emb_pos, eg, eb, hB);

  for (int l = 0; l < 2; l++) {
    const size_t lw = (size_t)l * 7077888;
    // QKV: 128x128 tiles
    gemm_nt<1><<<dim3(18, 64), 256, 0, stream>>>(hB, wt + lw, bq + l * 768, bk + l * 768,
                                                 bv + l * 768, qkvB, nullptr,
                                                 MM, QKVN, 768);
    attn_win<<<dim3(SS / QB, 12, 2), 256, 0, stream>>>(qkvB, mask, ctxB);
    attn_r0_part<<<dim3(16, 12, 2), 256, 0, stream>>>(qkvB, mask, r0part);
    attn_r0_comb<<<dim3(12, 2), 64, 0, stream>>>(r0part, ctxB);
    // Wo: split-K=2, bf16 partials
    gemm_nt<0><<<dim3(6, 64, 2), 256, 0, stream>>>(ctxB, wt + lw + 1769472, bo + l * 768,
                                                   nullptr, nullptr, d1, d2,
                                                   MM, 768, 768);
    ln_res<<<MM, 256, 0, stream>>>(hB, d1, d2, ln1g + l * 768, ln1b + l * 768);
    // FFN1: fused GELU
    gemm_nt<2><<<dim3(24, 64), 256, 0, stream>>>(hB, wt + lw + 2359296, b1 + l * 3072,
                                                 nullptr, nullptr, f1B, nullptr,
                                                 MM, 3072, 768);
    // FFN2: split-K=2, bf16 partials
    gemm_nt<0><<<dim3(6, 64, 2), 256, 0, stream>>>(f1B, wt + lw + 4718592, b2 + l * 768,
                                                   nullptr, nullptr, d1, d2,
                                                   MM, 768, 3072);
    ln_res<<<MM, 256, 0, stream>>>(hB, d1, d2, ln2g + l * 768, ln2b + l * 768);
  }

  cls_head<<<dim3(BB), 256, 0, stream>>>(hB, clsW, clsb, out);
}